// Round 1
// baseline (108.237 us; speedup 1.0000x reference)
//
#include <hip/hip_runtime.h>
#include <math.h>

#define BB 8
#define TT 2048
#define FF 67
#define DD 64
#define JITTER 1e-6f

// ---------------- kernel 1: per-row stats -----------------------------------
// mean[b,t] = x[b,t,0]
// c[b,t]    = v * exp(-0.5*||z||^2),  z = x[b,t,1:65]/8
// noise[b,t]= softplus(x[b,t,66])
__global__ __launch_bounds__(256) void row_stats_kernel(
    const float* __restrict__ in, float* __restrict__ out_mean,
    float* __restrict__ c, float* __restrict__ noise) {
  int idx = blockIdx.x * 256 + threadIdx.x;      // 0 .. B*T-1
  if (idx >= BB * TT) return;
  const float* row = in + (size_t)idx * FF;
  out_mean[idx] = row[0];
  float sq = 0.f;
#pragma unroll
  for (int d = 0; d < DD; ++d) {
    float z = row[1 + d] * 0.125f;
    sq = fmaf(z, z, sq);
  }
  float v = row[1 + DD];
  float x = row[1 + DD + 1];
  // stable softplus
  float sp = fmaxf(x, 0.f) + log1pf(__expf(-fabsf(x)));
  c[idx] = v * __expf(-0.5f * sq);
  noise[idx] = sp;
}

// ---------------- kernel 2: 64x64 covariance tiles --------------------------
__global__ __launch_bounds__(256) void cov_kernel(
    const float* __restrict__ in, const float* __restrict__ c,
    const float* __restrict__ noise, float* __restrict__ out_f,
    float* __restrict__ out_y) {
  __shared__ float zi[64][65];   // +1 pad: conflict-free scalar reads
  __shared__ float zj[64][65];
  __shared__ float ci_s[64], cj_s[64], ni_s[64];

  const int b = blockIdx.z;
  const int gi0 = blockIdx.y * 64;
  const int gj0 = blockIdx.x * 64;
  const int t = threadIdx.x;

  const float* zin_i = in + ((size_t)(b * TT + gi0) * FF) + 1;
  const float* zin_j = in + ((size_t)(b * TT + gj0) * FF) + 1;

  // stage 64 rows x 64 d for both tiles; lanes contiguous in d -> coalesced
#pragma unroll
  for (int k = 0; k < 16; ++k) {
    int idx = t + k * 256;
    int r = idx >> 6, d = idx & 63;
    zi[r][d] = zin_i[(size_t)r * FF + d] * 0.125f;
    zj[r][d] = zin_j[(size_t)r * FF + d] * 0.125f;
  }
  if (t < 64) {
    ci_s[t] = c[b * TT + gi0 + t];
    ni_s[t] = noise[b * TT + gi0 + t];
    cj_s[t] = c[b * TT + gj0 + t];
  }
  __syncthreads();

  const int tx = t & 15, ty = t >> 4;
  const int i0 = ty * 4, j0 = tx * 4;

  float acc[4][4] = {};
#pragma unroll
  for (int d = 0; d < DD; ++d) {
    float a0 = zi[i0 + 0][d], a1 = zi[i0 + 1][d];
    float a2 = zi[i0 + 2][d], a3 = zi[i0 + 3][d];
    float b0 = zj[j0 + 0][d], b1 = zj[j0 + 1][d];
    float b2 = zj[j0 + 2][d], b3 = zj[j0 + 3][d];
    acc[0][0] = fmaf(a0, b0, acc[0][0]);
    acc[0][1] = fmaf(a0, b1, acc[0][1]);
    acc[0][2] = fmaf(a0, b2, acc[0][2]);
    acc[0][3] = fmaf(a0, b3, acc[0][3]);
    acc[1][0] = fmaf(a1, b0, acc[1][0]);
    acc[1][1] = fmaf(a1, b1, acc[1][1]);
    acc[1][2] = fmaf(a1, b2, acc[1][2]);
    acc[1][3] = fmaf(a1, b3, acc[1][3]);
    acc[2][0] = fmaf(a2, b0, acc[2][0]);
    acc[2][1] = fmaf(a2, b1, acc[2][1]);
    acc[2][2] = fmaf(a2, b2, acc[2][2]);
    acc[2][3] = fmaf(a2, b3, acc[2][3]);
    acc[3][0] = fmaf(a3, b0, acc[3][0]);
    acc[3][1] = fmaf(a3, b1, acc[3][1]);
    acc[3][2] = fmaf(a3, b2, acc[3][2]);
    acc[3][3] = fmaf(a3, b3, acc[3][3]);
  }

  const size_t TTT = (size_t)TT * TT;
#pragma unroll
  for (int a = 0; a < 4; ++a) {
    int gi = gi0 + i0 + a;
    float cia = ci_s[i0 + a];
    float nia = ni_s[i0 + a];
    float fb[4], yb[4];
#pragma unroll
    for (int q = 0; q < 4; ++q) {
      int gj = gj0 + j0 + q;
      float f = __expf(acc[a][q]) * cia * cj_s[j0 + q];
      float y = f;
      if (gi == gj) { f += JITTER; y = f + nia; }
      fb[q] = f;
      yb[q] = y;
    }
    size_t off = (size_t)b * TTT + (size_t)gi * TT + (size_t)(gj0 + j0);
    *reinterpret_cast<float4*>(out_f + off) =
        make_float4(fb[0], fb[1], fb[2], fb[3]);
    *reinterpret_cast<float4*>(out_y + off) =
        make_float4(yb[0], yb[1], yb[2], yb[3]);
  }
}

extern "C" void kernel_launch(void* const* d_in, const int* in_sizes, int n_in,
                              void* d_out, int out_size, void* d_ws,
                              size_t ws_size, hipStream_t stream) {
  const float* in = (const float*)d_in[0];
  float* out = (float*)d_out;
  float* c = (float*)d_ws;                 // B*T floats
  float* noise = c + BB * TT;              // B*T floats
  float* out_mean = out;                   // B*T
  float* out_f = out + BB * TT;            // B*T*T
  float* out_y = out_f + (size_t)BB * TT * TT;  // B*T*T

  row_stats_kernel<<<(BB * TT) / 256, 256, 0, stream>>>(in, out_mean, c, noise);
  cov_kernel<<<dim3(TT / 64, TT / 64, BB), 256, 0, stream>>>(in, c, noise,
                                                             out_f, out_y);
}

// Round 2
// 86.434 us; speedup vs baseline: 1.2523x; 1.2523x over previous
//
#include <hip/hip_runtime.h>
#include <math.h>

#define BB 8
#define TT 2048
#define FF 67
#define DD 64
#define BT (BB * TT)
#define JITTER 1e-6f

// ---------------- kernel A: pack scaled z + per-row stats --------------------
// 16 lanes per row; zp[row][d] = in[row][1+d]/8 (16B-aligned, coalesced)
// c[row] = v * exp(-0.5*||z||^2); noise = softplus; mean passthrough.
__global__ __launch_bounds__(256) void pack_stats_kernel(
    const float* __restrict__ in, float* __restrict__ out_mean,
    float* __restrict__ c, float* __restrict__ noise,
    float* __restrict__ zp) {
  int g = blockIdx.x * 256 + threadIdx.x;   // 0 .. BT*16-1
  int row = g >> 4, dc = g & 15;
  const float* p = in + (size_t)row * FF + 1 + dc * 4;
  float z0 = p[0] * 0.125f, z1 = p[1] * 0.125f;
  float z2 = p[2] * 0.125f, z3 = p[3] * 0.125f;
  *reinterpret_cast<float4*>(zp + (size_t)row * DD + dc * 4) =
      make_float4(z0, z1, z2, z3);
  float sq = z0 * z0 + z1 * z1 + z2 * z2 + z3 * z3;
  sq += __shfl_xor(sq, 1);
  sq += __shfl_xor(sq, 2);
  sq += __shfl_xor(sq, 4);
  sq += __shfl_xor(sq, 8);
  if (dc == 0) {
    const float* r = in + (size_t)row * FF;
    out_mean[row] = r[0];
    float v = r[1 + DD];
    float x = r[1 + DD + 1];
    float sp = fmaxf(x, 0.f) + log1pf(__expf(-fabsf(x)));
    c[row] = v * __expf(-0.5f * sq);
    noise[row] = sp;
  }
}

// ---------------- fallback per-row stats (small ws) --------------------------
__global__ __launch_bounds__(256) void row_stats_kernel(
    const float* __restrict__ in, float* __restrict__ out_mean,
    float* __restrict__ c, float* __restrict__ noise) {
  int idx = blockIdx.x * 256 + threadIdx.x;
  if (idx >= BT) return;
  const float* row = in + (size_t)idx * FF;
  out_mean[idx] = row[0];
  float sq = 0.f;
#pragma unroll
  for (int d = 0; d < DD; ++d) {
    float z = row[1 + d] * 0.125f;
    sq = fmaf(z, z, sq);
  }
  float v = row[1 + DD];
  float x = row[1 + DD + 1];
  float sp = fmaxf(x, 0.f) + log1pf(__expf(-fabsf(x)));
  c[idx] = v * __expf(-0.5f * sq);
  noise[idx] = sp;
}

// ---------------- kernel B: triangular 128x128 covariance tiles --------------
// block: 256 threads (16x16), 8x8 micro-tile, float4 d-chunks,
// XOR-swizzled LDS so both zi (4 quads) and zj (2-way) reads are conflict-free.
template <bool PACKED>
__global__ __launch_bounds__(256, 2) void cov_kernel(
    const float* __restrict__ in, const float* __restrict__ zp,
    const float* __restrict__ c, const float* __restrict__ noise,
    float* __restrict__ out_f, float* __restrict__ out_y) {
  __shared__ float4 zi4[128 * 16];   // 32 KB
  __shared__ float4 zj4[128 * 16];   // 32 KB

  // decode triangular tile index k -> (ti, tj), tj <= ti, 16 tiles per dim
  int k = blockIdx.x;
  int ti = (int)((sqrtf(8.f * (float)k + 1.f) - 1.f) * 0.5f);
  if ((ti + 1) * (ti + 2) / 2 <= k) ++ti;
  if (ti * (ti + 1) / 2 > k) --ti;
  int tj = k - ti * (ti + 1) / 2;
  const int b = blockIdx.y;
  const int gi0 = ti * 128, gj0 = tj * 128;
  const int t = threadIdx.x;
  const bool diag = (ti == tj);

  // ---- stage both 128x64 panels into swizzled LDS ----
#pragma unroll
  for (int kk = 0; kk < 8; ++kk) {
    int idx = kk * 256 + t;
    int row = idx >> 4, dc = idx & 15;
    int sw = (row >> 3) & 7;
    float4 a4, b4;
    if (PACKED) {
      a4 = *reinterpret_cast<const float4*>(
          zp + ((size_t)(b * TT + gi0 + row)) * DD + dc * 4);
      b4 = *reinterpret_cast<const float4*>(
          zp + ((size_t)(b * TT + gj0 + row)) * DD + dc * 4);
    } else {
      const float* pa = in + (size_t)(b * TT + gi0 + row) * FF + 1 + dc * 4;
      const float* pb = in + (size_t)(b * TT + gj0 + row) * FF + 1 + dc * 4;
      a4 = make_float4(pa[0] * 0.125f, pa[1] * 0.125f, pa[2] * 0.125f,
                       pa[3] * 0.125f);
      b4 = make_float4(pb[0] * 0.125f, pb[1] * 0.125f, pb[2] * 0.125f,
                       pb[3] * 0.125f);
    }
    zi4[row * 16 + (dc ^ sw)] = a4;
    zj4[row * 16 + (dc ^ sw)] = b4;
  }
  __syncthreads();

  const int tx = t & 15, ty = t >> 4;
  const int i0 = ty * 8, j0 = tx * 8;
  const int swi = ty & 7, swj = tx & 7;   // == ((i0+a)>>3)&7, ((j0+q)>>3)&7

  float acc[8][8] = {};
  for (int dc = 0; dc < 16; ++dc) {
    float4 af[8], bf[8];
#pragma unroll
    for (int a = 0; a < 8; ++a) af[a] = zi4[(i0 + a) * 16 + (dc ^ swi)];
#pragma unroll
    for (int q = 0; q < 8; ++q) bf[q] = zj4[(j0 + q) * 16 + (dc ^ swj)];
#pragma unroll
    for (int a = 0; a < 8; ++a)
#pragma unroll
      for (int q = 0; q < 8; ++q) {
        acc[a][q] = fmaf(af[a].x, bf[q].x, acc[a][q]);
        acc[a][q] = fmaf(af[a].y, bf[q].y, acc[a][q]);
        acc[a][q] = fmaf(af[a].z, bf[q].z, acc[a][q]);
        acc[a][q] = fmaf(af[a].w, bf[q].w, acc[a][q]);
      }
  }

  // ---- epilogue ----
  const float* cb = c + b * TT;
  float ci[8], cj[8];
#pragma unroll
  for (int a = 0; a < 8; ++a) ci[a] = cb[gi0 + i0 + a];
#pragma unroll
  for (int q = 0; q < 8; ++q) cj[q] = cb[gj0 + j0 + q];

  float f[8][8];
#pragma unroll
  for (int a = 0; a < 8; ++a)
#pragma unroll
    for (int q = 0; q < 8; ++q)
      f[a][q] = __expf(acc[a][q]) * ci[a] * cj[q];

  const size_t TTT = (size_t)TT * TT;
  const size_t obase = (size_t)b * TTT;

  if (!diag) {
    // off-diagonal: y == f exactly; write tile and its mirror
#pragma unroll
    for (int a = 0; a < 8; ++a) {
      size_t off = obase + (size_t)(gi0 + i0 + a) * TT + gj0 + j0;
      float4 lo = make_float4(f[a][0], f[a][1], f[a][2], f[a][3]);
      float4 hi = make_float4(f[a][4], f[a][5], f[a][6], f[a][7]);
      *reinterpret_cast<float4*>(out_f + off) = lo;
      *reinterpret_cast<float4*>(out_f + off + 4) = hi;
      *reinterpret_cast<float4*>(out_y + off) = lo;
      *reinterpret_cast<float4*>(out_y + off + 4) = hi;
    }
#pragma unroll
    for (int q = 0; q < 8; ++q) {
      size_t off = obase + (size_t)(gj0 + j0 + q) * TT + gi0 + i0;
      float4 lo = make_float4(f[0][q], f[1][q], f[2][q], f[3][q]);
      float4 hi = make_float4(f[4][q], f[5][q], f[6][q], f[7][q]);
      *reinterpret_cast<float4*>(out_f + off) = lo;
      *reinterpret_cast<float4*>(out_f + off + 4) = hi;
      *reinterpret_cast<float4*>(out_y + off) = lo;
      *reinterpret_cast<float4*>(out_y + off + 4) = hi;
    }
  } else {
    const float* nb = noise + b * TT;
    float ni[8];
#pragma unroll
    for (int a = 0; a < 8; ++a) ni[a] = nb[gi0 + i0 + a];
#pragma unroll
    for (int a = 0; a < 8; ++a) {
      int gi = gi0 + i0 + a;
      float fb[8], yb[8];
#pragma unroll
      for (int q = 0; q < 8; ++q) {
        int gj = gj0 + j0 + q;
        float ff = f[a][q];
        float yy = ff;
        if (gi == gj) { ff += JITTER; yy = ff + ni[a]; }
        fb[q] = ff;
        yb[q] = yy;
      }
      size_t off = obase + (size_t)gi * TT + gj0 + j0;
      *reinterpret_cast<float4*>(out_f + off) =
          make_float4(fb[0], fb[1], fb[2], fb[3]);
      *reinterpret_cast<float4*>(out_f + off + 4) =
          make_float4(fb[4], fb[5], fb[6], fb[7]);
      *reinterpret_cast<float4*>(out_y + off) =
          make_float4(yb[0], yb[1], yb[2], yb[3]);
      *reinterpret_cast<float4*>(out_y + off + 4) =
          make_float4(yb[4], yb[5], yb[6], yb[7]);
    }
  }
}

extern "C" void kernel_launch(void* const* d_in, const int* in_sizes, int n_in,
                              void* d_out, int out_size, void* d_ws,
                              size_t ws_size, hipStream_t stream) {
  const float* in = (const float*)d_in[0];
  float* out = (float*)d_out;
  float* c = (float*)d_ws;                  // BT floats
  float* noise = c + BT;                    // BT floats
  float* zp = noise + BT;                   // BT*DD floats (packed scaled z)
  float* out_mean = out;                    // BT
  float* out_f = out + BT;                  // BB*TT*TT
  float* out_y = out_f + (size_t)BB * TT * TT;

  const size_t need = (size_t)(2 * BT + (size_t)BT * DD) * sizeof(float);
  if (ws_size >= need) {
    pack_stats_kernel<<<(BT * 16) / 256, 256, 0, stream>>>(in, out_mean, c,
                                                           noise, zp);
    cov_kernel<true><<<dim3(136, BB), 256, 0, stream>>>(in, zp, c, noise,
                                                        out_f, out_y);
  } else {
    row_stats_kernel<<<BT / 256, 256, 0, stream>>>(in, out_mean, c, noise);
    cov_kernel<false><<<dim3(136, BB), 256, 0, stream>>>(in, zp, c, noise,
                                                         out_f, out_y);
  }
}

// Round 3
// 85.997 us; speedup vs baseline: 1.2586x; 1.0051x over previous
//
#include <hip/hip_runtime.h>
#include <math.h>

#define BB 8
#define TT 2048
#define FF 67
#define DD 64
#define BT (BB * TT)
#define JITTER 1e-6f

// ---------------- kernel A: pack scaled z + per-row stats --------------------
__global__ __launch_bounds__(256) void pack_stats_kernel(
    const float* __restrict__ in, float* __restrict__ out_mean,
    float* __restrict__ c, float* __restrict__ noise,
    float* __restrict__ zp) {
  int g = blockIdx.x * 256 + threadIdx.x;   // 0 .. BT*16-1
  int row = g >> 4, dc = g & 15;
  const float* p = in + (size_t)row * FF + 1 + dc * 4;
  float z0 = p[0] * 0.125f, z1 = p[1] * 0.125f;
  float z2 = p[2] * 0.125f, z3 = p[3] * 0.125f;
  *reinterpret_cast<float4*>(zp + (size_t)row * DD + dc * 4) =
      make_float4(z0, z1, z2, z3);
  float sq = z0 * z0 + z1 * z1 + z2 * z2 + z3 * z3;
  sq += __shfl_xor(sq, 1);
  sq += __shfl_xor(sq, 2);
  sq += __shfl_xor(sq, 4);
  sq += __shfl_xor(sq, 8);
  if (dc == 0) {
    const float* r = in + (size_t)row * FF;
    out_mean[row] = r[0];
    float v = r[1 + DD];
    float x = r[1 + DD + 1];
    float sp = fmaxf(x, 0.f) + log1pf(__expf(-fabsf(x)));
    c[row] = v * __expf(-0.5f * sq);
    noise[row] = sp;
  }
}

// ---------------- fallback per-row stats (small ws) --------------------------
__global__ __launch_bounds__(256) void row_stats_kernel(
    const float* __restrict__ in, float* __restrict__ out_mean,
    float* __restrict__ c, float* __restrict__ noise) {
  int idx = blockIdx.x * 256 + threadIdx.x;
  if (idx >= BT) return;
  const float* row = in + (size_t)idx * FF;
  out_mean[idx] = row[0];
  float sq = 0.f;
#pragma unroll
  for (int d = 0; d < DD; ++d) {
    float z = row[1 + d] * 0.125f;
    sq = fmaf(z, z, sq);
  }
  float v = row[1 + DD];
  float x = row[1 + DD + 1];
  float sp = fmaxf(x, 0.f) + log1pf(__expf(-fabsf(x)));
  c[idx] = v * __expf(-0.5f * sq);
  noise[idx] = sp;
}

// fs swizzle: float j of row i lives at phys = i*128 + 4*((j>>2) ^ ((i>>2)&31)) + (j&3)
__device__ __forceinline__ int fs_idx(int i, int jchunk) {
  return i * 32 + (jchunk ^ ((i >> 2) & 31));   // in float4 units
}

// ---------------- kernel B: triangular 128x128 covariance tiles --------------
template <bool PACKED>
__global__ __launch_bounds__(256, 2) void cov_kernel(
    const float* __restrict__ in, const float* __restrict__ zp,
    const float* __restrict__ c, const float* __restrict__ noise,
    float* __restrict__ out_f, float* __restrict__ out_y) {
  __shared__ float4 smem[4096];   // 64 KB: z panels during compute, f-tile after
  float4* zi4 = smem;             // 128*16
  float4* zj4 = smem + 2048;      // 128*16

  // tile ordering: blocks 0..119 = strict lower (heavy), 120..135 = diag (light, last)
  int k = blockIdx.x;
  int ti, tj;
  if (k < 120) {
    ti = (int)((1.0f + sqrtf(1.0f + 8.0f * (float)k)) * 0.5f);
    while (ti * (ti - 1) / 2 > k) --ti;
    while ((ti + 1) * ti / 2 <= k) ++ti;
    tj = k - ti * (ti - 1) / 2;
  } else {
    ti = tj = k - 120;
  }
  const int b = blockIdx.y;
  const int gi0 = ti * 128, gj0 = tj * 128;
  const int t = threadIdx.x;
  const bool diag = (ti == tj);

  // ---- stage both 128x64 z panels into swizzled LDS ----
#pragma unroll
  for (int kk = 0; kk < 8; ++kk) {
    int idx = kk * 256 + t;
    int row = idx >> 4, dc = idx & 15;
    int sw = (row >> 3) & 7;
    float4 a4, b4;
    if (PACKED) {
      a4 = *reinterpret_cast<const float4*>(
          zp + ((size_t)(b * TT + gi0 + row)) * DD + dc * 4);
      b4 = *reinterpret_cast<const float4*>(
          zp + ((size_t)(b * TT + gj0 + row)) * DD + dc * 4);
    } else {
      const float* pa = in + (size_t)(b * TT + gi0 + row) * FF + 1 + dc * 4;
      const float* pb = in + (size_t)(b * TT + gj0 + row) * FF + 1 + dc * 4;
      a4 = make_float4(pa[0] * 0.125f, pa[1] * 0.125f, pa[2] * 0.125f,
                       pa[3] * 0.125f);
      b4 = make_float4(pb[0] * 0.125f, pb[1] * 0.125f, pb[2] * 0.125f,
                       pb[3] * 0.125f);
    }
    zi4[row * 16 + (dc ^ sw)] = a4;
    zj4[row * 16 + (dc ^ sw)] = b4;
  }
  __syncthreads();

  const int tx = t & 15, ty = t >> 4;
  const int i0 = ty * 8, j0 = tx * 8;
  const int swi = ty & 7, swj = tx & 7;

  float acc[8][8] = {};
  for (int dc = 0; dc < 16; ++dc) {
    float4 af[8], bf[8];
#pragma unroll
    for (int a = 0; a < 8; ++a) af[a] = zi4[(i0 + a) * 16 + (dc ^ swi)];
#pragma unroll
    for (int q = 0; q < 8; ++q) bf[q] = zj4[(j0 + q) * 16 + (dc ^ swj)];
#pragma unroll
    for (int a = 0; a < 8; ++a)
#pragma unroll
      for (int q = 0; q < 8; ++q) {
        acc[a][q] = fmaf(af[a].x, bf[q].x, acc[a][q]);
        acc[a][q] = fmaf(af[a].y, bf[q].y, acc[a][q]);
        acc[a][q] = fmaf(af[a].z, bf[q].z, acc[a][q]);
        acc[a][q] = fmaf(af[a].w, bf[q].w, acc[a][q]);
      }
  }

  // ---- f = exp(acc)*ci*cj in registers ----
  const float* cb = c + b * TT;
  float ci[8], cj[8];
#pragma unroll
  for (int a = 0; a < 8; ++a) ci[a] = cb[gi0 + i0 + a];
#pragma unroll
  for (int q = 0; q < 8; ++q) cj[q] = cb[gj0 + j0 + q];
#pragma unroll
  for (int a = 0; a < 8; ++a)
#pragma unroll
    for (int q = 0; q < 8; ++q)
      acc[a][q] = __expf(acc[a][q]) * ci[a] * cj[q];

  // ---- stage f-tile into LDS (aliases the dead z panels) ----
  __syncthreads();   // everyone done reading z
  float4* fs = smem;
#pragma unroll
  for (int a = 0; a < 8; ++a) {
    int row = i0 + a;
    fs[fs_idx(row, 2 * tx)] =
        make_float4(acc[a][0], acc[a][1], acc[a][2], acc[a][3]);
    fs[fs_idx(row, 2 * tx + 1)] =
        make_float4(acc[a][4], acc[a][5], acc[a][6], acc[a][7]);
  }
  __syncthreads();

  const size_t TTT = (size_t)TT * TT;
  const size_t obase = (size_t)b * TTT;
  const float* fss = (const float*)smem;

  // ---- direct tile: row-major, fully coalesced (64 lanes x 16B contiguous) --
#pragma unroll
  for (int it = 0; it < 16; ++it) {
    int g = it * 256 + t;
    int row = g >> 5, m = g & 31;         // row 0..127, 16B-chunk 0..31
    float4 v = fs[fs_idx(row, m)];
    float4 y = v;
    if (diag) {
      int e = row - 4 * m;                // diagonal element within chunk?
      if (e >= 0 && e < 4) {
        float nz = noise[b * TT + gi0 + row];
        float* vp = &v.x;
        float* yp = &y.x;
        vp[e] += JITTER;
        yp[e] = vp[e] + nz;
      }
    }
    size_t off = obase + (size_t)(gi0 + row) * TT + gj0 + 4 * m;
    *reinterpret_cast<float4*>(out_f + off) = v;
    *reinterpret_cast<float4*>(out_y + off) = y;
  }

  // ---- mirror tile (off-diag only): transposed gather from LDS, coalesced --
  if (!diag) {
#pragma unroll
    for (int it = 0; it < 16; ++it) {
      int g = it * 256 + t;
      int jrow = g >> 5, kc = g & 31;     // out row = col j, chunk over i
      float4 v;
      float* vp = &v.x;
#pragma unroll
      for (int e = 0; e < 4; ++e) {
        int i = 4 * kc + e;
        vp[e] = fss[i * 128 + 4 * ((jrow >> 2) ^ (kc & 31)) + (jrow & 3)];
      }
      size_t off = obase + (size_t)(gj0 + jrow) * TT + gi0 + 4 * kc;
      *reinterpret_cast<float4*>(out_f + off) = v;
      *reinterpret_cast<float4*>(out_y + off) = v;
    }
  }
}

extern "C" void kernel_launch(void* const* d_in, const int* in_sizes, int n_in,
                              void* d_out, int out_size, void* d_ws,
                              size_t ws_size, hipStream_t stream) {
  const float* in = (const float*)d_in[0];
  float* out = (float*)d_out;
  float* c = (float*)d_ws;                  // BT floats
  float* noise = c + BT;                    // BT floats
  float* zp = noise + BT;                   // BT*DD floats
  float* out_mean = out;                    // BT
  float* out_f = out + BT;                  // BB*TT*TT
  float* out_y = out_f + (size_t)BB * TT * TT;

  const size_t need = (size_t)(2 * BT + (size_t)BT * DD) * sizeof(float);
  if (ws_size >= need) {
    pack_stats_kernel<<<(BT * 16) / 256, 256, 0, stream>>>(in, out_mean, c,
                                                           noise, zp);
    cov_kernel<true><<<dim3(136, BB), 256, 0, stream>>>(in, zp, c, noise,
                                                        out_f, out_y);
  } else {
    row_stats_kernel<<<BT / 256, 256, 0, stream>>>(in, out_mean, c, noise);
    cov_kernel<false><<<dim3(136, BB), 256, 0, stream>>>(in, zp, c, noise,
                                                         out_f, out_y);
  }
}